// Round 5
// baseline (883.100 us; speedup 1.0000x reference)
//
#include <hip/hip_runtime.h>
#include <hip/hip_bf16.h>
#include <stdint.h>

// Problem constants (fixed by the reference).
constexpr int BATCH = 64;
constexpr int T     = 2048;
constexpr int CCH   = 32;
constexpr int OUT_T = 2048;
constexpr int K     = T * CCH;   // 65536
constexpr int N     = OUT_T;     // 2048

// GEMM tiling: flatmm (no LDS, no barriers). Block = 4 waves, 64m x 64n tile.
constexpr int TN     = 64;
constexpr int NBN    = N / TN;       // 32
constexpr int KSPLIT = 64;
constexpr int CK     = K / KSPLIT;   // 1024 k per block
constexpr int BK     = 32;           // K per MFMA step
constexpr int NS     = CK / BK;      // 32 steps
constexpr int NWG    = NBN * KSPLIT; // 2048 blocks

typedef __attribute__((ext_vector_type(8))) short short8;
typedef __attribute__((ext_vector_type(4))) float f32x4;

// Split fp32 pair -> packed bf16 hi (TRUNCATION) + packed bf16 lo (RNE).
// Bit-identical numerics to rounds 1-3.
__device__ __forceinline__ void split2t(float a, float b, unsigned& hpk, unsigned& lpk) {
  unsigned ua = __float_as_uint(a), ub = __float_as_uint(b);
  hpk = (ua >> 16) | (ub & 0xFFFF0000u);
  float la = a - __uint_as_float(ua & 0xFFFF0000u);
  float lb = b - __uint_as_float(ub & 0xFFFF0000u);
  __hip_bfloat162 l2 = __float22bfloat162_rn(make_float2(la, lb));  // v_cvt_pk_bf16_f32
  __builtin_memcpy(&lpk, &l2, 4);
}

// ---- Kernel 1: precompute X hi/lo bf16 planes (one pass over 16 MB) ----
__global__ __launch_bounds__(256) void xsplit_kernel(
    const float* __restrict__ X, ushort* __restrict__ Xhi, ushort* __restrict__ Xlo) {
  const int i = blockIdx.x * 256 + threadIdx.x;   // float4 index; 1M total
  const float4 v = ((const float4*)X)[i];
  unsigned h01, l01, h23, l23;
  split2t(v.x, v.y, h01, l01);
  split2t(v.z, v.w, h23, l23);
  uint2 hv; hv.x = h01; hv.y = h23;
  uint2 lv; lv.x = l01; lv.y = l23;
  ((uint2*)Xhi)[i] = hv;
  ((uint2*)Xlo)[i] = lv;
}

// ---- Kernel 2: barrier-free K-split flat GEMM ----
// B-fragments stream directly from W (global) with a 4-deep register pipeline;
// A-fragments stream from presplit Xhi/Xlo (L2-resident) with a 2-deep pipeline.
__global__ __launch_bounds__(256) void gemm_flat_kernel(
    const ushort* __restrict__ Xhi,   // (64, 65536) bf16 hi plane
    const ushort* __restrict__ Xlo,   // (64, 65536) bf16 lo plane
    const float*  __restrict__ W,     // (65536, 2048) fp32
    float* __restrict__ def) {        // (64, 2048) fp32, pre-zeroed
  // XCD-aware bijective swizzle (2048 % 8 == 0): XCD x owns bk in [8x, 8x+8)
  // -> per-XCD Xsplit working set = 8 x 256 KB = 2 MB, L2-resident.
  const int bid = blockIdx.x;                       // 0..2047
  const int lb  = (bid & 7) * (NWG / 8) + (bid >> 3);
  const int bn  = lb & (NBN - 1);                   // 0..31
  const int bk  = lb >> 5;                          // 0..63

  const int tid  = threadIdx.x;
  const int lane = tid & 63;
  const int wave = tid >> 6;                        // wave owns n-cols [16w, 16w+16)
  const int r = lane & 15;
  const int g = lane >> 4;

  const int kbase = bk * CK;
  const int ncol  = bn * TN + wave * 16 + r;

  // B-operand per lane: W[k0 + 8g + j][ncol], j = 0..7 (k-contiguous fragment).
  const float* wbase = W + (size_t)(kbase + 8 * g) * N + ncol;

  f32x4 acc[4] = {};                // 4 m-frags x 16 n
  float b0[8], b1[8], b2[8], b3[8]; // 4-deep raw-W pipeline
  short8 a0h[4], a0l[4], a1h[4], a1l[4]; // 2-deep A-fragment pipeline

  auto issueB = [&](int t, float (&bb)[8]) {
    const float* p = wbase + (size_t)t * (BK * N);
#pragma unroll
    for (int j = 0; j < 8; ++j) bb[j] = p[(size_t)j * N];
  };

  auto issueA = [&](int t, short8 (&ah)[4], short8 (&al)[4]) {
    const unsigned off = (unsigned)(((size_t)r * K + kbase + t * BK + 8 * g) * 2);
#pragma unroll
    for (int mf = 0; mf < 4; ++mf) {
      ah[mf] = *(const short8*)((const char*)Xhi + off + (size_t)mf * (16 * K * 2));
      al[mf] = *(const short8*)((const char*)Xlo + off + (size_t)mf * (16 * K * 2));
    }
  };

  auto domfma = [&](float (&bb)[8], short8 (&ah)[4], short8 (&al)[4]) {
    union { short8 s; unsigned u[4]; } bh, bl;
#pragma unroll
    for (int p2 = 0; p2 < 4; ++p2)
      split2t(bb[2 * p2], bb[2 * p2 + 1], bh.u[p2], bl.u[p2]);
#pragma unroll
    for (int mf = 0; mf < 4; ++mf) {
      acc[mf] = __builtin_amdgcn_mfma_f32_16x16x32_bf16(ah[mf], bh.s, acc[mf], 0, 0, 0);
      acc[mf] = __builtin_amdgcn_mfma_f32_16x16x32_bf16(ah[mf], bl.s, acc[mf], 0, 0, 0);
      acc[mf] = __builtin_amdgcn_mfma_f32_16x16x32_bf16(al[mf], bh.s, acc[mf], 0, 0, 0);
    }
  };

  // Prologue: B 4 steps ahead, A 2 steps ahead.
  issueB(0, b0); issueB(1, b1); issueB(2, b2); issueB(3, b3);
  issueA(0, a0h, a0l); issueA(1, a1h, a1l);

  // Main loop: branch-free body, modulo-4 B slots / modulo-2 A slots.
  for (int t = 0; t < NS - 4; t += 4) {   // t = 0,4,...,24
    domfma(b0, a0h, a0l); issueB(t + 4, b0); issueA(t + 2, a0h, a0l);
    domfma(b1, a1h, a1l); issueB(t + 5, b1); issueA(t + 3, a1h, a1l);
    domfma(b2, a0h, a0l); issueB(t + 6, b2); issueA(t + 4, a0h, a0l);
    domfma(b3, a1h, a1l); issueB(t + 7, b3); issueA(t + 5, a1h, a1l);
  }
  // Epilogue: steps 28..31 (B(28..31) already in flight; A(28),A(29) in slots).
  domfma(b0, a0h, a0l); issueA(30, a0h, a0l);
  domfma(b1, a1h, a1l); issueA(31, a1h, a1l);
  domfma(b2, a0h, a0l);
  domfma(b3, a1h, a1l);

  // Epilogue: atomically accumulate K-split partials.
  // C/D layout: col = lane&15 (n), row = 4*(lane>>4) + reg (m within 16-frag).
#pragma unroll
  for (int mf = 0; mf < 4; ++mf) {
    const int mbase = mf * 16 + g * 4;
#pragma unroll
    for (int q = 0; q < 4; ++q) {
      atomicAdd(&def[(size_t)(mbase + q) * N + ncol], acc[mf][q]);
    }
  }
}

// ---- Kernel 3: resample (unchanged, verified) ----
__global__ __launch_bounds__(256) void resample_kernel(
    const float* __restrict__ X,       // (64, 2048, 32)
    const float* __restrict__ def,     // (64, 2048)
    const float* __restrict__ b_loc,   // (2048,)
    float* __restrict__ out) {         // (64, 2048, 32)
  const int tid = blockIdx.x * 256 + threadIdx.x;  // 64*2048*8 total
  const int c4 = tid & 7;
  const int o  = (tid >> 3) & (OUT_T - 1);
  const int b  = tid >> 14;

  const float x = (float)o + def[b * OUT_T + o] + b_loc[o];
  const float xf = floorf(x);
  const int x0 = (int)xf;
  const int x1 = x0 + 1;
  const int x0c = min(max(x0, 0), T - 1);
  const int x1c = min(max(x1, 0), T - 1);
  const float w0 = (float)x1c - x;    // weights use CLIPPED coords (faithful)
  const float w1 = x - (float)x0c;

  const float4 v0 = *(const float4*)&X[((size_t)b * T + x0c) * CCH + c4 * 4];
  const float4 v1 = *(const float4*)&X[((size_t)b * T + x1c) * CCH + c4 * 4];
  float4 res;
  res.x = w0 * v0.x + w1 * v1.x;
  res.y = w0 * v0.y + w1 * v1.y;
  res.z = w0 * v0.z + w1 * v1.z;
  res.w = w0 * v0.w + w1 * v1.w;
  *(float4*)&out[((size_t)b * OUT_T + o) * CCH + c4 * 4] = res;
}

extern "C" void kernel_launch(void* const* d_in, const int* in_sizes, int n_in,
                              void* d_out, int out_size, void* d_ws, size_t ws_size,
                              hipStream_t stream) {
  const float* X     = (const float*)d_in[0];
  const float* W     = (const float*)d_in[1];
  const float* b_loc = (const float*)d_in[2];
  float* out = (float*)d_out;

  // d_ws layout: def (512 KB) @0, Xhi (8 MB) @1MB, Xlo (8 MB) @9MB.
  float*  def = (float*)d_ws;
  ushort* Xhi = (ushort*)((char*)d_ws + (1u << 20));
  ushort* Xlo = (ushort*)((char*)d_ws + (1u << 20) + (size_t)BATCH * K * 2);

  hipMemsetAsync(def, 0, (size_t)BATCH * N * sizeof(float), stream);

  xsplit_kernel<<<(BATCH * K / 4) / 256, 256, 0, stream>>>(X, Xhi, Xlo);

  gemm_flat_kernel<<<NWG, 256, 0, stream>>>(Xhi, Xlo, W, def);

  resample_kernel<<<(BATCH * OUT_T * 8) / 256, 256, 0, stream>>>(X, def, b_loc, out);
}

// Round 7
// 734.219 us; speedup vs baseline: 1.2028x; 1.2028x over previous
//
#include <hip/hip_runtime.h>
#include <hip/hip_bf16.h>
#include <stdint.h>

// Problem constants (fixed by the reference).
constexpr int BATCH = 64;
constexpr int T     = 2048;
constexpr int CCH   = 32;
constexpr int OUT_T = 2048;
constexpr int K     = T * CCH;   // 65536
constexpr int N     = OUT_T;     // 2048

// GEMM tiling: 64m x 64n block tile, 4 waves; wave w owns m-rows [16w,16w+16).
constexpr int TN     = 64;
constexpr int NBN    = N / TN;       // 32
constexpr int KSPLIT = 64;
constexpr int CK     = K / KSPLIT;   // 1024 k per block
constexpr int BK     = 32;           // K per step
constexpr int NS     = CK / BK;      // 32 steps
constexpr int NWG    = NBN * KSPLIT; // 2048 blocks

typedef __attribute__((ext_vector_type(8))) short short8;
typedef __attribute__((ext_vector_type(4))) float f32x4;

// Split fp32 pair -> packed bf16 hi (TRUNCATION) + packed bf16 lo (RNE).
// Bit-identical numerics to rounds 1-5 (absmax must stay 0.015625).
__device__ __forceinline__ void split2t(float a, float b, unsigned& hpk, unsigned& lpk) {
  unsigned ua = __float_as_uint(a), ub = __float_as_uint(b);
  hpk = (ua >> 16) | (ub & 0xFFFF0000u);
  float la = a - __uint_as_float(ua & 0xFFFF0000u);
  float lb = b - __uint_as_float(ub & 0xFFFF0000u);
  __hip_bfloat162 l2 = __float22bfloat162_rn(make_float2(la, lb));  // v_cvt_pk_bf16_f32
  __builtin_memcpy(&lpk, &l2, 4);
}

// ---- Kernel 1: precompute X hi/lo bf16 planes (one pass over 16 MB) ----
__global__ __launch_bounds__(256) void xsplit_kernel(
    const float* __restrict__ X, ushort* __restrict__ Xhi, ushort* __restrict__ Xlo) {
  const int i = blockIdx.x * 256 + threadIdx.x;   // float4 index; 1M total
  const float4 v = ((const float4*)X)[i];
  unsigned h01, l01, h23, l23;
  split2t(v.x, v.y, h01, l01);
  split2t(v.z, v.w, h23, l23);
  uint2 hv; hv.x = h01; hv.y = h23;
  uint2 lv; lv.x = l01; lv.y = l23;
  ((uint2*)Xhi)[i] = hv;
  ((uint2*)Xlo)[i] = lv;
}

// ---- Kernel 2: K-split GEMM. A per-wave direct from L2 (presplit planes);
// B (the HBM stream) through double-buffered LDS with a 3-deep W reg pipeline.
__global__ __launch_bounds__(256) void gemm_kernel(
    const ushort* __restrict__ Xhi,   // (64, 65536) bf16 hi plane
    const ushort* __restrict__ Xlo,   // (64, 65536) bf16 lo plane
    const float*  __restrict__ W,     // (65536, 2048) fp32
    float* __restrict__ def) {        // (64, 2048) fp32, pre-zeroed
  // XCD-aware bijective swizzle (2048 % 8 == 0): XCD x owns bk in [8x, 8x+8)
  // with all 32 bn -> X slice (2 MB) L2-resident; the 32 bn-blocks of one bk
  // run together on one XCD so their 256 B W-row slices merge into full rows.
  const int bid = blockIdx.x;                       // 0..2047
  const int lb  = (bid & 7) * (NWG / 8) + (bid >> 3);
  const int bn  = lb & (NBN - 1);                   // 0..31
  const int bk  = lb >> 5;                          // 0..63

  const int tid  = threadIdx.x;
  const int lane = tid & 63;
  const int wave = tid >> 6;                        // owns m-rows [16w, 16w+16)
  const int r = lane & 15;
  const int g = lane >> 4;

  // LDS: B^T tiles only (64n x 32k), bf16 hi/lo, double-buffered. 20 KB.
  __shared__ ushort Bhi[2][64][40];   // stride 40 ushort = 80 B (16B-aligned rows)
  __shared__ ushort Blo[2][64][40];

  f32x4 acc[4] = {};                  // 4 n-frags; acc[f] = C[16w+4g+q][bn*64+16f+r]
  const int kbase = bk * CK;

  // A source: row = wave*16 + r, k = kbase + t*BK + 8g (fragment k = 8g + j).
  const char* aBaseH = (const char*)Xhi + ((size_t)(wave * 16 + r) * K + kbase + 8 * g) * 2;
  const char* aBaseL = (const char*)Xlo + ((size_t)(wave * 16 + r) * K + kbase + 8 * g) * 2;

  // W cooperative load coords: thread covers (n = tid&63, kq0 = tid>>6) and
  // the second half-tile at kq0+4.  k index = kq*4 + j.
  const int nW  = tid & 63;
  const int kq0 = tid >> 6;           // 0..3
  const float* wBase = W + (size_t)(kbase + kq0 * 4) * N + bn * TN + nW;

  // 3-deep W register slots, 3-deep A slots (named vars -> no scratch).
  float  w0[8], w1[8], w2[8];
  short8 a0h, a0l, a1h, a1l, a2h, a2l;

  auto issueW = [&](int t, float (&s)[8]) {
    const float* p = wBase + (size_t)t * BK * N;
#pragma unroll
    for (int j = 0; j < 4; ++j) {
      s[j]     = p[(size_t)j * N];          // k = kq0*4 + j
      s[4 + j] = p[(size_t)(16 + j) * N];   // k = 16 + kq0*4 + j
    }
  };

  auto issueA = [&](int t, short8& ah, short8& al) {
    ah = *(const short8*)(aBaseH + (size_t)t * BK * 2);
    al = *(const short8*)(aBaseL + (size_t)t * BK * 2);
  };

  auto stageB = [&](int buf, float (&s)[8]) {
    unsigned h01, l01, h23, l23;
    split2t(s[0], s[1], h01, l01);
    split2t(s[2], s[3], h23, l23);
    uint2 hv; hv.x = h01; hv.y = h23;
    uint2 lv; lv.x = l01; lv.y = l23;
    *(uint2*)&Bhi[buf][nW][kq0 * 4] = hv;
    *(uint2*)&Blo[buf][nW][kq0 * 4] = lv;
    split2t(s[4], s[5], h01, l01);
    split2t(s[6], s[7], h23, l23);
    uint2 hv2; hv2.x = h01; hv2.y = h23;
    uint2 lv2; lv2.x = l01; lv2.y = l23;
    *(uint2*)&Bhi[buf][nW][(kq0 + 4) * 4] = hv2;
    *(uint2*)&Blo[buf][nW][(kq0 + 4) * 4] = lv2;
  };

  auto mfma_step = [&](int buf, short8& ah, short8& al) {
#pragma unroll
    for (int f = 0; f < 4; ++f) {
      short8 bh = *(const short8*)&Bhi[buf][f * 16 + r][g * 8];
      short8 bl = *(const short8*)&Blo[buf][f * 16 + r][g * 8];
      acc[f] = __builtin_amdgcn_mfma_f32_16x16x32_bf16(ah, bh, acc[f], 0, 0, 0);
      acc[f] = __builtin_amdgcn_mfma_f32_16x16x32_bf16(ah, bl, acc[f], 0, 0, 0);
      acc[f] = __builtin_amdgcn_mfma_f32_16x16x32_bf16(al, bh, acc[f], 0, 0, 0);
    }
  };

  // One step: issue W(t+3) & A(t+2) early, compute t, stage t+1, 1 barrier.
  auto dostep = [&](int t, float (&wsNext)[8], float (&wsStage)[8],
                    short8& ahC, short8& alC, short8& ahN, short8& alN, int buf) {
    if (t + 3 < NS) issueW(t + 3, wsNext);
    if (t + 2 < NS) issueA(t + 2, ahN, alN);
    mfma_step(buf, ahC, alC);
    if (t + 1 < NS) stageB(buf ^ 1, wsStage);   // waits vmcnt on W(t+1) (issued t-2)
    __syncthreads();
  };

  // Prologue: W(0..2) in flight, A(0..1) in flight, stage B(0).
  issueW(0, w0); issueW(1, w1); issueW(2, w2);
  issueA(0, a0h, a0l); issueA(1, a1h, a1l);
  stageB(0, w0);
  __syncthreads();

  // Main loop, period 6 (W slots mod 3, LDS bufs mod 2). Steps 0..29.
#pragma unroll
  for (int tb = 0; tb < 30; tb += 6) {
    dostep(tb + 0, w0, w1, a0h, a0l, a2h, a2l, 0);
    dostep(tb + 1, w1, w2, a1h, a1l, a0h, a0l, 1);
    dostep(tb + 2, w2, w0, a2h, a2l, a1h, a1l, 0);
    dostep(tb + 3, w0, w1, a0h, a0l, a2h, a2l, 1);
    dostep(tb + 4, w1, w2, a1h, a1l, a0h, a0l, 0);
    dostep(tb + 5, w2, w0, a2h, a2l, a1h, a1l, 1);
  }
  dostep(30, w0, w1, a0h, a0l, a2h, a2l, 0);
  dostep(31, w1, w2, a1h, a1l, a0h, a0l, 1);

  // Epilogue: atomically accumulate K-split partials.
  // acc[f][q] = C[m = 16*wave + 4g + q][n = bn*64 + 16f + r].
  const int mrow = wave * 16 + g * 4;
#pragma unroll
  for (int f = 0; f < 4; ++f) {
    const int ncol = bn * TN + f * 16 + r;
#pragma unroll
    for (int q = 0; q < 4; ++q) {
      atomicAdd(&def[(size_t)(mrow + q) * N + ncol], acc[f][q]);
    }
  }
}

// ---- Kernel 3: resample (unchanged, verified) ----
__global__ __launch_bounds__(256) void resample_kernel(
    const float* __restrict__ X,       // (64, 2048, 32)
    const float* __restrict__ def,     // (64, 2048)
    const float* __restrict__ b_loc,   // (2048,)
    float* __restrict__ out) {         // (64, 2048, 32)
  const int tid = blockIdx.x * 256 + threadIdx.x;  // 64*2048*8 total
  const int c4 = tid & 7;
  const int o  = (tid >> 3) & (OUT_T - 1);
  const int b  = tid >> 14;

  const float x = (float)o + def[b * OUT_T + o] + b_loc[o];
  const float xf = floorf(x);
  const int x0 = (int)xf;
  const int x1 = x0 + 1;
  const int x0c = min(max(x0, 0), T - 1);
  const int x1c = min(max(x1, 0), T - 1);
  const float w0 = (float)x1c - x;    // weights use CLIPPED coords (faithful)
  const float w1 = x - (float)x0c;

  const float4 v0 = *(const float4*)&X[((size_t)b * T + x0c) * CCH + c4 * 4];
  const float4 v1 = *(const float4*)&X[((size_t)b * T + x1c) * CCH + c4 * 4];
  float4 res;
  res.x = w0 * v0.x + w1 * v1.x;
  res.y = w0 * v0.y + w1 * v1.y;
  res.z = w0 * v0.z + w1 * v1.z;
  res.w = w0 * v0.w + w1 * v1.w;
  *(float4*)&out[((size_t)b * OUT_T + o) * CCH + c4 * 4] = res;
}

extern "C" void kernel_launch(void* const* d_in, const int* in_sizes, int n_in,
                              void* d_out, int out_size, void* d_ws, size_t ws_size,
                              hipStream_t stream) {
  const float* X     = (const float*)d_in[0];
  const float* W     = (const float*)d_in[1];
  const float* b_loc = (const float*)d_in[2];
  float* out = (float*)d_out;

  // d_ws layout: def (512 KB) @0, Xhi (8 MB) @1MB, Xlo (8 MB) @9MB.
  float*  def = (float*)d_ws;
  ushort* Xhi = (ushort*)((char*)d_ws + (1u << 20));
  ushort* Xlo = (ushort*)((char*)d_ws + (1u << 20) + (size_t)BATCH * K * 2);

  hipMemsetAsync(def, 0, (size_t)BATCH * N * sizeof(float), stream);

  xsplit_kernel<<<(BATCH * K / 4) / 256, 256, 0, stream>>>(X, Xhi, Xlo);

  gemm_kernel<<<NWG, 256, 0, stream>>>(Xhi, Xlo, W, def);

  resample_kernel<<<(BATCH * OUT_T * 8) / 256, 256, 0, stream>>>(X, def, b_loc, out);
}